// Round 1
// baseline (116.909 us; speedup 1.0000x reference)
//
#include <hip/hip_runtime.h>

// DWT1D Haar analysis, B=32, N=4096, C=64 (fp32).
//
// Flat-index identity (verified): for output pair index p in [0, out_elems/8):
//   c4 = p & 15   (float4 within the 64-float channel row)
//   bk = p >> 4   (b*half + k)
//   idx0 = bk*32 + c4 = p + (p & ~15)    -> input row 2k   (float4 units)
//   idx1 = idx0 + 16                     -> input row 2k+1
//   out4[idx0] = s*(x0 + x1)   (L band, out[b,k,0:C])
//   out4[idx1] = s*(x0 - x1)   (H band, out[b,k,C:2C])
//
// Haar taps are compile-time constants: the reference builds A from
// h0 = [s, s], h1 = [s, -s], s = 1/sqrt(2) -- deterministic, so no A loads.
// Pure streaming: 33.55 MB read + 33.55 MB write, memory-bound.
// Each thread handles 2 independent pairs (64 B in / 64 B out) for MLP.

__device__ __forceinline__ float4 haar_lo(const float4 a, const float4 b, float s) {
    return make_float4(s * (a.x + b.x), s * (a.y + b.y),
                       s * (a.z + b.z), s * (a.w + b.w));
}
__device__ __forceinline__ float4 haar_hi(const float4 a, const float4 b, float s) {
    return make_float4(s * (a.x - b.x), s * (a.y - b.y),
                       s * (a.z - b.z), s * (a.w - b.w));
}

__global__ __launch_bounds__(256) void dwt1d_haar_kernel(
    const float4* __restrict__ x4,
    float4* __restrict__ out4,
    int total_pairs)   // out_elems / 8; one pair = one (lo,hi) float4 duo
{
    constexpr float s = 0.70710678118654752440f;  // 1/sqrt(2)

    const int stride = gridDim.x * blockDim.x;
    const int p0 = blockIdx.x * blockDim.x + threadIdx.x;
    const int p1 = p0 + stride;

    if (p1 < total_pairs) {
        // Two independent pairs: 4 loads in flight before any compute.
        const int i0 = p0 + (p0 & ~15);
        const int j0 = p1 + (p1 & ~15);
        const float4 a0 = x4[i0];
        const float4 a1 = x4[i0 + 16];
        const float4 b0 = x4[j0];
        const float4 b1 = x4[j0 + 16];
        out4[i0]      = haar_lo(a0, a1, s);
        out4[i0 + 16] = haar_hi(a0, a1, s);
        out4[j0]      = haar_lo(b0, b1, s);
        out4[j0 + 16] = haar_hi(b0, b1, s);
    } else if (p0 < total_pairs) {
        const int i0 = p0 + (p0 & ~15);
        const float4 a0 = x4[i0];
        const float4 a1 = x4[i0 + 16];
        out4[i0]      = haar_lo(a0, a1, s);
        out4[i0 + 16] = haar_hi(a0, a1, s);
    }
}

extern "C" void kernel_launch(void* const* d_in, const int* in_sizes, int n_in,
                              void* d_out, int out_size, void* d_ws, size_t ws_size,
                              hipStream_t stream) {
    const float* x = (const float*)d_in[0];
    // d_in[1] (A) is deterministic Haar -- taps are compile-time constants.
    float* out = (float*)d_out;

    // out_size is in elements (verified last session: byte-interpretation would
    // have mis-derived N and failed the check). One pair = 8 output floats.
    const int total = out_size / 8;
    const int block = 256;
    const int per_block = block * 2;   // 2 pairs per thread
    const int grid = (total + per_block - 1) / per_block;

    dwt1d_haar_kernel<<<grid, block, 0, stream>>>(
        (const float4*)x, (float4*)out, total);
}